// Round 1
// baseline (187.115 us; speedup 1.0000x reference)
//
#include <hip/hip_runtime.h>
#include <hip/hip_bf16.h>

typedef __bf16 bf16x8 __attribute__((ext_vector_type(8)));
typedef float floatx4 __attribute__((ext_vector_type(4)));

#define BATCH 256
#define INDIM 512
#define ODIM 10
#define HTOT 18432
#define NMODEL 128
#define HTILE 64
#define BK 32
#define LSTRIDE 56   // bf16 elems per LDS row (32 data + pad -> 112 B: conflict-free b128 frag reads)
#define ACT_CHUNK 4608

__device__ __forceinline__ unsigned pk2(float a, float b) {
    unsigned ua = __float_as_uint(a);
    ua = (ua + 0x7fffu + ((ua >> 16) & 1u)) >> 16;
    unsigned ub = __float_as_uint(b);
    ub = (ub + 0x7fffu + ((ub >> 16) & 1u)) >> 16;
    return ua | (ub << 16);
}

__device__ __forceinline__ float apply_act(float h, int aidx) {
    if (aidx == 0) return fmaxf(h, 0.f);
    if (aidx == 1) return 1.f - 2.f / (1.f + __expf(2.f * h));   // tanh, no-overflow form
    if (aidx == 2) return 1.f / (1.f + __expf(-h));              // sigmoid
    return h;                                                     // identity
}

__global__ void init_out_kernel(const float* __restrict__ out_b, float* __restrict__ out) {
    int i = blockIdx.x * 256 + threadIdx.x;   // 327680 total
    out[i] = out_b[i % (NMODEL * ODIM)];
}

__global__ __launch_bounds__(256) void mlp_kernel(
    const float* __restrict__ x, const float* __restrict__ hidden_w,
    const float* __restrict__ hidden_b, const float* __restrict__ out_w,
    const int* __restrict__ hidden_ids, float* __restrict__ out)
{
    __shared__ unsigned short xs[BATCH * LSTRIDE];   // 28 KB
    __shared__ unsigned short wsx[HTILE * LSTRIDE];  // 7 KB
    __shared__ float wtile[ODIM * HTILE];            // 2.5 KB, [o][64]
    __shared__ float btile[HTILE];

    const int tid = threadIdx.x;
    const int j0 = blockIdx.x * HTILE;
    const int lane = tid & 63;
    const int wv = tid >> 6;      // wave id 0..3 -> b-range [64*wv, 64*wv+64)
    const int r = lane & 15;
    const int g = lane >> 4;

    // stage out_w tile + bias (used only in epilogue; first __syncthreads covers it)
    for (int i = tid; i < ODIM * HTILE; i += 256)
        wtile[i] = out_w[(i >> 6) * HTOT + j0 + (i & 63)];
    if (tid < HTILE) btile[tid] = hidden_b[j0 + tid];

    floatx4 acc[4][4];
    #pragma unroll
    for (int jt = 0; jt < 4; jt++)
        #pragma unroll
        for (int bt = 0; bt < 4; bt++)
            acc[jt][bt] = (floatx4)0.f;

    const floatx4* xv  = (const floatx4*)x;
    const floatx4* wv4 = (const floatx4*)hidden_w;

    for (int kk = 0; kk < INDIM; kk += BK) {
        const int kq = kk >> 2;
        // stage x chunk: 256 rows x 32 k (2048 float4, 8 per thread), fp32 -> bf16
        #pragma unroll
        for (int i = 0; i < 8; i++) {
            int f = tid + i * 256;
            int row = f >> 3, c4 = f & 7;
            floatx4 v = xv[row * (INDIM / 4) + kq + c4];
            *(uint2*)&xs[row * LSTRIDE + c4 * 4] = make_uint2(pk2(v[0], v[1]), pk2(v[2], v[3]));
        }
        // stage w chunk: 64 rows x 32 k (512 float4, 2 per thread)
        #pragma unroll
        for (int i = 0; i < 2; i++) {
            int f = tid + i * 256;
            int row = f >> 3, c4 = f & 7;
            floatx4 v = wv4[(size_t)(j0 + row) * (INDIM / 4) + kq + c4];
            *(uint2*)&wsx[row * LSTRIDE + c4 * 4] = make_uint2(pk2(v[0], v[1]), pk2(v[2], v[3]));
        }
        __syncthreads();

        bf16x8 af[4], bfr[4];
        #pragma unroll
        for (int jt = 0; jt < 4; jt++)
            af[jt] = *(const bf16x8*)&wsx[(jt * 16 + r) * LSTRIDE + g * 8];
        #pragma unroll
        for (int bt = 0; bt < 4; bt++)
            bfr[bt] = *(const bf16x8*)&xs[(wv * 64 + bt * 16 + r) * LSTRIDE + g * 8];
        #pragma unroll
        for (int jt = 0; jt < 4; jt++)
            #pragma unroll
            for (int bt = 0; bt < 4; bt++)
                acc[jt][bt] = __builtin_amdgcn_mfma_f32_16x16x32_bf16(af[jt], bfr[bt], acc[jt][bt], 0, 0, 0);
        __syncthreads();
    }

    // Epilogue. D layout: n(=b) = lane&15, m(=j within 16-tile) = (lane>>4)*4 + reg.
    // Segment boundaries are all multiples of 32 -> each aligned 32-j pair has ONE model id.
    const int aidx = j0 / ACT_CHUNK;   // uniform per block (4608 % 64 == 0)
    #pragma unroll
    for (int jp = 0; jp < 2; jp++) {
        const int mdl = hidden_ids[j0 + jp * 32];   // uniform
        floatx4 a4[2][4];
        #pragma unroll
        for (int h = 0; h < 2; h++) {
            int jt = jp * 2 + h;
            floatx4 bv = *(const floatx4*)&btile[jt * 16 + g * 4];
            #pragma unroll
            for (int bt = 0; bt < 4; bt++) {
                floatx4 c = acc[jt][bt];
                floatx4 t;
                #pragma unroll
                for (int q = 0; q < 4; q++) t[q] = apply_act(c[q] + bv[q], aidx);
                a4[h][bt] = t;
            }
        }
        #pragma unroll
        for (int o = 0; o < ODIM; o++) {
            floatx4 w0 = *(const floatx4*)&wtile[o * HTILE + jp * 32 + g * 4];
            floatx4 w1 = *(const floatx4*)&wtile[o * HTILE + jp * 32 + 16 + g * 4];
            #pragma unroll
            for (int bt = 0; bt < 4; bt++) {
                float p = a4[0][bt][0]*w0[0] + a4[0][bt][1]*w0[1] + a4[0][bt][2]*w0[2] + a4[0][bt][3]*w0[3]
                        + a4[1][bt][0]*w1[0] + a4[1][bt][1]*w1[1] + a4[1][bt][2]*w1[2] + a4[1][bt][3]*w1[3];
                p += __shfl_xor(p, 16, 64);
                p += __shfl_xor(p, 32, 64);
                if (lane < 16) {
                    int b = wv * 64 + bt * 16 + r;
                    atomicAdd(out + (size_t)b * (NMODEL * ODIM) + mdl * ODIM + o, p);
                }
            }
        }
    }
}

extern "C" void kernel_launch(void* const* d_in, const int* in_sizes, int n_in,
                              void* d_out, int out_size, void* d_ws, size_t ws_size,
                              hipStream_t stream) {
    const float* x   = (const float*)d_in[0];
    const float* hw  = (const float*)d_in[1];
    const float* hb  = (const float*)d_in[2];
    const float* ow  = (const float*)d_in[3];
    const float* ob  = (const float*)d_in[4];
    const int*   ids = (const int*)d_in[5];
    float* out = (float*)d_out;

    init_out_kernel<<<(BATCH * NMODEL * ODIM) / 256, 256, 0, stream>>>(ob, out);
    mlp_kernel<<<HTOT / HTILE, 256, 0, stream>>>(x, hw, hb, ow, ids, out);
}

// Round 2
// 184.828 us; speedup vs baseline: 1.0124x; 1.0124x over previous
//
#include <hip/hip_runtime.h>
#include <hip/hip_bf16.h>

typedef __bf16 bf16x8 __attribute__((ext_vector_type(8)));
typedef float floatx4 __attribute__((ext_vector_type(4)));

#define BATCH 256
#define INDIM 512
#define ODIM 10
#define HTOT 18432
#define NMODEL 128
#define HTILE 64
#define BTILE 64
#define BK 64
#define LSTRIDE 72   // bf16 elems per LDS row (64 data + 8 pad)
#define ACT_CHUNK 4608

__device__ __forceinline__ unsigned pk2(float a, float b) {
    unsigned ua = __float_as_uint(a);
    ua = (ua + 0x7fffu + ((ua >> 16) & 1u)) >> 16;
    unsigned ub = __float_as_uint(b);
    ub = (ub + 0x7fffu + ((ub >> 16) & 1u)) >> 16;
    return ua | (ub << 16);
}

__device__ __forceinline__ float apply_act(float h, int aidx) {
    if (aidx == 0) return fmaxf(h, 0.f);
    if (aidx == 1) return 1.f - 2.f / (1.f + __expf(2.f * h));   // tanh, no-overflow form
    if (aidx == 2) return 1.f / (1.f + __expf(-h));              // sigmoid
    return h;                                                     // identity
}

__global__ void init_out_kernel(const float* __restrict__ out_b, float* __restrict__ out) {
    int i = blockIdx.x * 256 + threadIdx.x;   // 327680 total
    out[i] = out_b[i % (NMODEL * ODIM)];
}

// grid = (HTOT/HTILE) * (BATCH/BTILE) = 288 * 4 = 1152 blocks, 256 threads.
// Each wave computes 64j x 16b via acc[4] (16x16x32 bf16 MFMA).
__global__ __launch_bounds__(256, 4) void mlp_kernel(
    const float* __restrict__ x, const float* __restrict__ hidden_w,
    const float* __restrict__ hidden_b, const float* __restrict__ out_w,
    const int* __restrict__ hidden_ids, float* __restrict__ out)
{
    __shared__ unsigned short xs[BTILE * LSTRIDE];   // 9216 B
    __shared__ unsigned short wsx[HTILE * LSTRIDE];  // 9216 B
    __shared__ float wtile[ODIM * HTILE];            // 2560 B, [o][64]
    __shared__ float btile[HTILE];

    const int tid = threadIdx.x;
    const int bid = blockIdx.x;
    const int jb = bid >> 2, bb = bid & 3;   // consecutive bids share the w-tile
    const int j0 = jb * HTILE;
    const int b0 = bb * BTILE;
    const int lane = tid & 63;
    const int wvid = tid >> 6;               // wave id 0..3 -> b-range [16*wvid, 16*wvid+16)
    const int r = lane & 15;
    const int g = lane >> 4;

    // stage out_w tile + bias (epilogue-only; first __syncthreads covers it)
    for (int i = tid; i < ODIM * HTILE; i += 256)
        wtile[i] = out_w[(i >> 6) * HTOT + j0 + (i & 63)];
    if (tid < HTILE) btile[tid] = hidden_b[j0 + tid];

    floatx4 acc[4];
    #pragma unroll
    for (int jt = 0; jt < 4; jt++) acc[jt] = (floatx4)0.f;

    const floatx4* xv  = (const floatx4*)x;
    const floatx4* wv4 = (const floatx4*)hidden_w;

    for (int kk = 0; kk < INDIM; kk += BK) {
        const int kq = kk >> 2;
        // stage x tile (64b x 64k) and w tile (64j x 64k): 1024 float4 each,
        // 4 + 4 per thread, fp32 -> bf16 packed
        #pragma unroll
        for (int i = 0; i < 4; i++) {
            int f = tid + i * 256;
            int row = f >> 4, c4 = f & 15;
            floatx4 v = xv[(size_t)(b0 + row) * (INDIM / 4) + kq + c4];
            floatx4 u = wv4[(size_t)(j0 + row) * (INDIM / 4) + kq + c4];
            *(uint2*)&xs[row * LSTRIDE + c4 * 4]  = make_uint2(pk2(v[0], v[1]), pk2(v[2], v[3]));
            *(uint2*)&wsx[row * LSTRIDE + c4 * 4] = make_uint2(pk2(u[0], u[1]), pk2(u[2], u[3]));
        }
        __syncthreads();

        #pragma unroll
        for (int s = 0; s < 2; s++) {
            bf16x8 bfr = *(const bf16x8*)&xs[(wvid * 16 + r) * LSTRIDE + s * 32 + g * 8];
            #pragma unroll
            for (int jt = 0; jt < 4; jt++) {
                bf16x8 af = *(const bf16x8*)&wsx[(jt * 16 + r) * LSTRIDE + s * 32 + g * 8];
                acc[jt] = __builtin_amdgcn_mfma_f32_16x16x32_bf16(af, bfr, acc[jt], 0, 0, 0);
            }
        }
        __syncthreads();
    }

    // Epilogue. D layout: col(b) = lane&15, row(j within 16-tile) = (lane>>4)*4 + reg.
    // Segment boundaries are multiples of 32 -> each aligned 32-j pair has ONE model id.
    const int aidx = j0 / ACT_CHUNK;             // uniform per block (4608 % 64 == 0)
    const int b = b0 + wvid * 16 + r;
    float* outb = out + (size_t)b * (NMODEL * ODIM);

    #pragma unroll
    for (int jp = 0; jp < 2; jp++) {
        const int mdl = hidden_ids[j0 + jp * 32];   // uniform per block
        float a[2][4];
        #pragma unroll
        for (int h = 0; h < 2; h++) {
            int jt = jp * 2 + h;
            #pragma unroll
            for (int q = 0; q < 4; q++)
                a[h][q] = apply_act(acc[jt][q] + btile[jt * 16 + g * 4 + q], aidx);
        }
        #pragma unroll
        for (int o = 0; o < ODIM; o++) {
            float p = 0.f;
            #pragma unroll
            for (int h = 0; h < 2; h++) {
                int jt = jp * 2 + h;
                const float* wr = &wtile[o * HTILE + jt * 16 + g * 4];
                p += a[h][0] * wr[0] + a[h][1] * wr[1] + a[h][2] * wr[2] + a[h][3] * wr[3];
            }
            p += __shfl_xor(p, 16, 64);
            p += __shfl_xor(p, 32, 64);
            if (lane < 16)
                atomicAdd(outb + mdl * ODIM + o, p);
        }
    }
}

extern "C" void kernel_launch(void* const* d_in, const int* in_sizes, int n_in,
                              void* d_out, int out_size, void* d_ws, size_t ws_size,
                              hipStream_t stream) {
    const float* x   = (const float*)d_in[0];
    const float* hw  = (const float*)d_in[1];
    const float* hb  = (const float*)d_in[2];
    const float* ow  = (const float*)d_in[3];
    const float* ob  = (const float*)d_in[4];
    const int*   ids = (const int*)d_in[5];
    float* out = (float*)d_out;

    init_out_kernel<<<(BATCH * NMODEL * ODIM) / 256, 256, 0, stream>>>(ob, out);
    mlp_kernel<<<(HTOT / HTILE) * (BATCH / BTILE), 256, 0, stream>>>(x, hw, hb, ow, ids, out);
}

// Round 3
// 114.591 us; speedup vs baseline: 1.6329x; 1.6129x over previous
//
#include <hip/hip_runtime.h>
#include <hip/hip_bf16.h>

typedef __bf16 bf16x8 __attribute__((ext_vector_type(8)));
typedef float floatx4 __attribute__((ext_vector_type(4)));

#define BATCH 256
#define INDIM 512
#define ODIM 10
#define HTOT 18432
#define NMODEL 128
#define HTILE 64
#define BTILE 64
#define BK 64
#define LSTRIDE 72   // bf16 elems per LDS row (64 data + 8 pad)
#define ACT_CHUNK 4608
#define NJPG (HTOT / 32)   // 576 aligned 32-neuron pairs

__device__ __forceinline__ unsigned pk2(float a, float b) {
    unsigned ua = __float_as_uint(a);
    ua = (ua + 0x7fffu + ((ua >> 16) & 1u)) >> 16;
    unsigned ub = __float_as_uint(b);
    ub = (ub + 0x7fffu + ((ub >> 16) & 1u)) >> 16;
    return ua | (ub << 16);
}

__device__ __forceinline__ float apply_act(float h, int aidx) {
    if (aidx == 0) return fmaxf(h, 0.f);
    if (aidx == 1) return 1.f - 2.f / (1.f + __expf(2.f * h));   // tanh, no-overflow form
    if (aidx == 2) return 1.f / (1.f + __expf(-h));              // sigmoid
    return h;                                                     // identity
}

// grid = (HTOT/HTILE) * (BATCH/BTILE) = 288 * 4 = 1152 blocks, 256 threads.
// Each wave computes 64j x 16b via acc[4] (16x16x32 bf16 MFMA).
// Partial per-(jpg,o,b) sums go to ws (NO atomics): ws[jpg][o][b].
__global__ __launch_bounds__(256, 4) void mlp_kernel(
    const float* __restrict__ x, const float* __restrict__ hidden_w,
    const float* __restrict__ hidden_b, const float* __restrict__ out_w,
    float* __restrict__ ws)
{
    __shared__ unsigned short xs[BTILE * LSTRIDE];   // 9216 B
    __shared__ unsigned short wsx[HTILE * LSTRIDE];  // 9216 B
    __shared__ float wtile[ODIM * HTILE];            // 2560 B, [o][64]
    __shared__ float btile[HTILE];

    const int tid = threadIdx.x;
    const int bid = blockIdx.x;
    const int jb = bid >> 2, bb = bid & 3;   // consecutive bids share the w-tile
    const int j0 = jb * HTILE;
    const int b0 = bb * BTILE;
    const int lane = tid & 63;
    const int wvid = tid >> 6;               // wave id 0..3 -> b-range [16*wvid, 16*wvid+16)
    const int r = lane & 15;
    const int g = lane >> 4;

    // stage out_w tile + bias (epilogue-only; first __syncthreads covers it)
    for (int i = tid; i < ODIM * HTILE; i += 256)
        wtile[i] = out_w[(i >> 6) * HTOT + j0 + (i & 63)];
    if (tid < HTILE) btile[tid] = hidden_b[j0 + tid];

    floatx4 acc[4];
    #pragma unroll
    for (int jt = 0; jt < 4; jt++) acc[jt] = (floatx4)0.f;

    const floatx4* xv  = (const floatx4*)x;
    const floatx4* wv4 = (const floatx4*)hidden_w;

    for (int kk = 0; kk < INDIM; kk += BK) {
        const int kq = kk >> 2;
        // stage x tile (64b x 64k) and w tile (64j x 64k): 1024 float4 each,
        // 4 + 4 per thread, fp32 -> bf16 packed
        #pragma unroll
        for (int i = 0; i < 4; i++) {
            int f = tid + i * 256;
            int row = f >> 4, c4 = f & 15;
            floatx4 v = xv[(size_t)(b0 + row) * (INDIM / 4) + kq + c4];
            floatx4 u = wv4[(size_t)(j0 + row) * (INDIM / 4) + kq + c4];
            *(uint2*)&xs[row * LSTRIDE + c4 * 4]  = make_uint2(pk2(v[0], v[1]), pk2(v[2], v[3]));
            *(uint2*)&wsx[row * LSTRIDE + c4 * 4] = make_uint2(pk2(u[0], u[1]), pk2(u[2], u[3]));
        }
        __syncthreads();

        #pragma unroll
        for (int s = 0; s < 2; s++) {
            bf16x8 bfr = *(const bf16x8*)&xs[(wvid * 16 + r) * LSTRIDE + s * 32 + g * 8];
            #pragma unroll
            for (int jt = 0; jt < 4; jt++) {
                bf16x8 af = *(const bf16x8*)&wsx[(jt * 16 + r) * LSTRIDE + s * 32 + g * 8];
                acc[jt] = __builtin_amdgcn_mfma_f32_16x16x32_bf16(af, bfr, acc[jt], 0, 0, 0);
            }
        }
        __syncthreads();
    }

    // Epilogue. D layout: col(b) = lane&15, row(j within 16-tile) = (lane>>4)*4 + reg.
    const int aidx = j0 / ACT_CHUNK;             // uniform per block (4608 % 64 == 0)
    const int b = b0 + wvid * 16 + r;

    #pragma unroll
    for (int jp = 0; jp < 2; jp++) {
        const int jpg = (j0 >> 5) + jp;          // global 32-pair index
        float a[2][4];
        #pragma unroll
        for (int h = 0; h < 2; h++) {
            int jt = jp * 2 + h;
            #pragma unroll
            for (int q = 0; q < 4; q++)
                a[h][q] = apply_act(acc[jt][q] + btile[jt * 16 + g * 4 + q], aidx);
        }
        #pragma unroll
        for (int o = 0; o < ODIM; o++) {
            float p = 0.f;
            #pragma unroll
            for (int h = 0; h < 2; h++) {
                int jt = jp * 2 + h;
                const float* wr = &wtile[o * HTILE + jt * 16 + g * 4];
                p += a[h][0] * wr[0] + a[h][1] * wr[1] + a[h][2] * wr[2] + a[h][3] * wr[3];
            }
            p += __shfl_xor(p, 16, 64);
            p += __shfl_xor(p, 32, 64);
            if (lane < 16)
                ws[((size_t)jpg * ODIM + o) * BATCH + b] = p;   // plain store, one owner
        }
    }
}

// One block per (model, o): 1280 blocks x 256 threads (thread = b).
// Sums the model's 1..8 jp partials + out_b, writes out[b][m][o] once.
__global__ __launch_bounds__(256) void finalize_kernel(
    const float* __restrict__ ws, const float* __restrict__ out_b,
    float* __restrict__ out)
{
    const int mo = blockIdx.x;           // m*ODIM + o
    const int m = mo / ODIM, o = mo - m * ODIM;
    const int b = threadIdx.x;
    // model m -> structure pattern: rep = m/8, idx = m%8, size = 32*(idx+1)
    const int rep = m >> 3, idx = m & 7;
    const int jp0 = rep * 36 + (idx * (idx + 1)) / 2;
    const int cnt = idx + 1;

    float s = out_b[mo];
    for (int c = 0; c < cnt; c++)
        s += ws[((size_t)(jp0 + c) * ODIM + o) * BATCH + b];
    out[((size_t)b * NMODEL + m) * ODIM + o] = s;
}

extern "C" void kernel_launch(void* const* d_in, const int* in_sizes, int n_in,
                              void* d_out, int out_size, void* d_ws, size_t ws_size,
                              hipStream_t stream) {
    const float* x   = (const float*)d_in[0];
    const float* hw  = (const float*)d_in[1];
    const float* hb  = (const float*)d_in[2];
    const float* ow  = (const float*)d_in[3];
    const float* ob  = (const float*)d_in[4];
    float* out = (float*)d_out;
    float* ws  = (float*)d_ws;           // NJPG * ODIM * BATCH * 4 = 5.9 MB

    mlp_kernel<<<(HTOT / HTILE) * (BATCH / BTILE), 256, 0, stream>>>(x, hw, hb, ow, ws);
    finalize_kernel<<<NMODEL * ODIM, 256, 0, stream>>>(ws, ob, out);
}